// Round 14
// baseline (244.561 us; speedup 1.0000x reference)
//
#include <hip/hip_runtime.h>

#define NB 4
#define NP 900
#define ND 512
#define NH 8
#define NDK 64
#define NROWS (NB*NP)          // 3600
#define SSZ (NP*NP)            // 810000
#define NBH (NB*NH)            // 32
#define SIDE 30

typedef unsigned short ushort_t;
typedef unsigned char uchar_t;
typedef unsigned long long u64_t;
typedef __attribute__((ext_vector_type(8)))  _Float16 h8v;
typedef __attribute__((ext_vector_type(4)))  float  f4v;
typedef __attribute__((ext_vector_type(16))) float  f16v;

__device__ __forceinline__ ushort_t f2h(float f) {
    union { _Float16 h; ushort_t u; } c; c.h = (_Float16)f; return c.u;
}
__device__ __forceinline__ float h2f(ushort_t u) {
    union { _Float16 h; ushort_t u; } c; c.u = u; return (float)c.h;
}
// order-preserving f32 -> u32 (total order; equal floats -> equal codes)
__device__ __forceinline__ unsigned int fenc(float v) {
    unsigned int b = __float_as_uint(v);
    return (b & 0x80000000u) ? ~b : (b | 0x80000000u);
}

// split one float4 into fp16 hi/lo and store to a 128-ushort LDS row (swizzled 16B chunks)
__device__ __forceinline__ void split_store(char* rowp, int r, int c4, float4 v) {
    const int ch  = (c4 >> 1) ^ (r & 7);
    const int off = (c4 & 1) * 8;
    const float f[4] = {v.x, v.y, v.z, v.w};
    ushort_t hi[4], lo[4];
    #pragma unroll
    for (int j = 0; j < 4; ++j) {
        hi[j] = f2h(f[j]);
        lo[j] = f2h(f[j] - h2f(hi[j]));
    }
    uint2 u;
    u.x = (unsigned)hi[0] | ((unsigned)hi[1] << 16);
    u.y = (unsigned)hi[2] | ((unsigned)hi[3] << 16);
    *(uint2*)(rowp + ch*16 + off) = u;
    u.x = (unsigned)lo[0] | ((unsigned)lo[1] << 16);
    u.y = (unsigned)lo[2] | ((unsigned)lo[3] << 16);
    *(uint2*)(rowp + (ch + 8)*16 + off) = u;
}

// ---------------- projection via split-fp16 MFMA (3-term ~= f32 exact) ----------------
// out = X · W^T + bias, written PRE-SPLIT in PACKED [bh][p][hi 0..63 | lo 64..127] fp16
// layout (r11-proven). Bias folded into accumulator init. Absorbs prep_weights (x==57).
__global__ __launch_bounds__(256, 3) void proj_kernel(
    const float* __restrict__ query, const float* __restrict__ key_t,
    const float* __restrict__ Wq, const float* __restrict__ bq,
    const float* __restrict__ Wk, const float* __restrict__ bk,
    ushort_t* __restrict__ Qhl, ushort_t* __restrict__ Khl,
    const float* __restrict__ c1w, const float* __restrict__ c2w,
    ushort_t* __restrict__ w1b, ushort_t* __restrict__ w2b,
    u64_t* __restrict__ amax)
{
    // ---- folded prep_weights: grid.x==57 slot (one working block, others exit) ----
    if (blockIdx.x == 57) {
        if (blockIdx.z == 1 && blockIdx.y == 0) {
            const int tid = threadIdx.x;
            for (int i = tid; i < 5*64; i += 256) {
                const int c = i >> 6, l = i & 63;
                const int oc = l & 31, hf = l >> 5;
                #pragma unroll
                for (int j = 0; j < 8; ++j) {
                    float wv;
                    if (c < 4)      wv = c1w[(oc*8 + j)*9 + (2*c + hf)];
                    else            wv = hf ? 0.f : c1w[(oc*8 + j)*9 + 8];
                    w1b[(i)*8 + j] = f2h(wv);
                }
            }
            for (int i = tid; i < 9*64; i += 256) {
                const int t = i >> 6, l = i & 63;
                const int n = l & 15, qd = l >> 4;
                #pragma unroll
                for (int j = 0; j < 8; ++j) {
                    const int k = qd*8 + j;
                    const float wv = (n < 8) ? c2w[(n*32 + k)*9 + t] : 0.f;
                    w2b[(i)*8 + j] = f2h(wv);
                }
            }
        }
        return;
    }

    __shared__ __align__(16) ushort_t As[64][128];    // 16 KB: [row][hi 0..63 | lo 64..127]
    __shared__ __align__(16) ushort_t Bs[128][128];   // 32 KB

    const float *X, *W, *bias;
    ushort_t *Ohl;
    if (blockIdx.z == 0) { X = query; W = Wq; bias = bq; Ohl = Qhl; }
    else                 { X = key_t; W = Wk; bias = bk; Ohl = Khl; }

    // fused amax zeroing (stream-ordered before scores_kernel); 228 blocks cover 28800
    if (blockIdx.z == 0) {
        const int t = (blockIdx.y * 57 + blockIdx.x) * 256 + threadIdx.x;
        if (t < NBH * NP) amax[t] = 0ull;
    }

    const int m0 = blockIdx.x * 64;      // row tile (57 tiles over 3600)
    const int n0 = blockIdx.y * 128;     // col tile (4 tiles over 512)
    const int tid  = threadIdx.x;
    const int lane = tid & 63;
    const int w    = tid >> 6;
    const int ln = lane & 31, lh = lane >> 5;
    const int wr = (w >> 1) * 32;        // wave: 32 rows x 64 cols
    const int wc = (w & 1) * 64;

    f16v acc[2];
    #pragma unroll
    for (int cb = 0; cb < 2; ++cb) {
        const float bv = bias[n0 + wc + cb*32 + ln];
        #pragma unroll
        for (int r = 0; r < 16; ++r) acc[cb][r] = bv;
    }

    auto ldA = [&](int row, int ch) -> h8v {
        return *(const h8v*)((const char*)&As[row][0] + ((ch ^ (row & 7)) << 4));
    };
    auto ldB = [&](int row, int ch) -> h8v {
        return *(const h8v*)((const char*)&Bs[row][0] + ((ch ^ (row & 7)) << 4));
    };

    for (int kt = 0; kt < 8; ++kt) {
        const int kb = kt * 64;
        #pragma unroll
        for (int i = 0; i < 4; ++i) {
            const int idx = tid + i * 256;           // 0..1023 : A rows
            const int r = idx >> 4, c4 = idx & 15;
            float4 v = make_float4(0.f, 0.f, 0.f, 0.f);
            if (m0 + r < NROWS) v = *(const float4*)(X + (size_t)(m0 + r) * ND + kb + c4*4);
            split_store((char*)&As[r][0], r, c4, v);
        }
        #pragma unroll
        for (int i = 0; i < 8; ++i) {
            const int idx = tid + i * 256;           // 0..2047 : B rows (W rows, always valid)
            const int r = idx >> 4, c4 = idx & 15;
            const float4 v = *(const float4*)(W + (size_t)(n0 + r) * ND + kb + c4*4);
            split_store((char*)&Bs[r][0], r, c4, v);
        }
        __syncthreads();

        #pragma unroll
        for (int ks = 0; ks < 4; ++ks) {
            const int chH = ks*2 + lh;
            const h8v a_h = ldA(wr + ln, chH);
            const h8v a_l = ldA(wr + ln, chH + 8);
            #pragma unroll
            for (int cb = 0; cb < 2; ++cb) {
                const int col = wc + cb*32 + ln;
                const h8v b_h = ldB(col, chH);
                const h8v b_l = ldB(col, chH + 8);
                acc[cb] = __builtin_amdgcn_mfma_f32_32x32x16_f16(a_h, b_h, acc[cb], 0, 0, 0);
                acc[cb] = __builtin_amdgcn_mfma_f32_32x32x16_f16(a_h, b_l, acc[cb], 0, 0, 0);
                acc[cb] = __builtin_amdgcn_mfma_f32_32x32x16_f16(a_l, b_h, acc[cb], 0, 0, 0);
            }
        }
        __syncthreads();
    }

    // epilogue: split to fp16 hi/lo, packed row layout [bh][p][hi|lo]
    #pragma unroll
    for (int cb = 0; cb < 2; ++cb) {
        const int col = n0 + wc + cb*32 + ln;
        const int h = col >> 6, dk = col & 63;
        #pragma unroll
        for (int r = 0; r < 16; ++r) {
            const int gi = m0 + wr + ((r & 3) + 8*(r >> 2) + 4*lh);
            if (gi < NROWS) {
                const int bb = gi / NP, p = gi - bb * NP;
                const float v = acc[cb][r];
                const ushort_t hi = f2h(v);
                const ushort_t lo = f2h(v - h2f(hi));
                ushort_t* dst = Ohl + ((size_t)(bb*NH + h)*NP + p)*128 + dk;
                dst[0]  = hi;
                dst[64] = lo;
            }
        }
    }
}

// ---------------- scores via split-fp16 MFMA (3-term compensation ~= f32 exact) ----------
// S = Qh*Kh + Qh*Kl + Ql*Kh  (Ql*Kl ~ 2^-22 relative, dropped).
// r12-proven: 64(p) x 128(q) tile, 49KB LDS -> 3 blocks/CU. Staging is pure copy
// (r11 packed layout). Fused per-column argmax; stores S as fp16.
__global__ __launch_bounds__(256, 3) void scores_kernel(
    const ushort_t* __restrict__ Qhl, const ushort_t* __restrict__ Khl,
    ushort_t* __restrict__ Sh, u64_t* __restrict__ amax)
{
    __shared__ __align__(16) ushort_t Qs[64][128];    // 16 KB: [row][0..63]=hi, [64..127]=lo
    __shared__ __align__(16) ushort_t Ks[128][128];   // 32 KB
    __shared__ u64_t amax_s[128];

    // XCD-contiguous swizzle: 3840 blocks -> 480-block chunks per XCD (bijective)
    const int lin = blockIdx.x;
    const int swz = (lin & 7) * 480 + (lin >> 3);
    const int bh  = swz / 120;                 // 120 tiles per head (15 p x 8 q)
    const int tt  = swz - bh * 120;
    const int p0  = (tt >> 3) * 64;            // query-row tile (15 tiles over 900)
    const int q0  = (tt & 7) * 128;            // key-col tile

    const ushort_t* Qhlb = Qhl + (size_t)bh * NP * 128;
    const ushort_t* Khlb = Khl + (size_t)bh * NP * 128;
    const int tid  = threadIdx.x;
    const int lane = tid & 63;
    const int w    = tid >> 6;

    if (tid < 128) amax_s[tid] = 0ull;

    // ---- stage (pure copy): Q 64 rows + K 128 rows, 16 b128 chunks each; 12/thread ----
    #pragma unroll
    for (int i = 0; i < 12; ++i) {
        const int idx = tid + i * 256;          // 0..3071 (idx<1024 -> Q, else K)
        int r, c8;
        const ushort_t* src;
        char* rowp;
        int base;
        if (idx < 1024) {
            r = idx >> 4; c8 = idx & 15;
            src = Qhlb; rowp = (char*)&Qs[r][0]; base = p0;
        } else {
            const int k = idx - 1024;
            r = k >> 4; c8 = k & 15;
            src = Khlb; rowp = (char*)&Ks[r][0]; base = q0;
        }
        uint4 v = make_uint4(0u,0u,0u,0u);
        if (base + r < NP) v = *(const uint4*)(src + (size_t)(base + r)*128 + c8*8);
        const int ch = ((c8 & 7) ^ (r & 7)) | (c8 & 8);
        *(uint4*)(rowp + ch*16) = v;
    }
    __syncthreads();

    const int ln = lane & 31;
    const int lh = lane >> 5;
    const int wr = (w & 1) * 32;    // wave rows (32 of 64)
    const int wc = (w >> 1) * 64;   // wave cols (64 of 128)

    auto ldQ = [&](int row, int ch) -> h8v {
        return *(const h8v*)((const char*)&Qs[row][0] + ((ch ^ (row & 7)) << 4));
    };
    auto ldK = [&](int row, int ch) -> h8v {
        return *(const h8v*)((const char*)&Ks[row][0] + ((ch ^ (row & 7)) << 4));
    };

    f16v acc[2] = {};

    #pragma unroll
    for (int ks = 0; ks < 4; ++ks) {
        const int chH = ks*2 + lh;          // hi chunk for this lane-half; lo = chH+8
        const h8v ah = ldQ(wr + ln, chH);
        const h8v al = ldQ(wr + ln, chH + 8);
        #pragma unroll
        for (int cb = 0; cb < 2; ++cb) {
            const int col = wc + cb*32 + ln;
            const h8v bh_ = ldK(col, chH);
            const h8v bl_ = ldK(col, chH + 8);
            acc[cb] = __builtin_amdgcn_mfma_f32_32x32x16_f16(ah, bh_, acc[cb], 0, 0, 0);
            acc[cb] = __builtin_amdgcn_mfma_f32_32x32x16_f16(ah, bl_, acc[cb], 0, 0, 0);
            acc[cb] = __builtin_amdgcn_mfma_f32_32x32x16_f16(al, bh_, acc[cb], 0, 0, 0);
        }
    }

    // ---- epilogue: fp16 store + fused column argmax ----
    ushort_t* Sb = Sh + (size_t)bh * SSZ;
    #pragma unroll
    for (int cb = 0; cb < 2; ++cb) {
        const int lq = wc + cb*32 + ln;
        const int gq = q0 + lq;
        if (gq < NP) {
            u64_t key = 0ull;
            #pragma unroll
            for (int r = 0; r < 16; ++r) {
                const int gp = p0 + wr + ((r & 3) + 8*(r >> 2) + 4*lh);
                if (gp < NP) {
                    const float v = acc[cb][r];
                    Sb[(size_t)gp * NP + gq] = f2h(v);
                    const u64_t kk = ((u64_t)fenc(v) << 32) | (unsigned)(899 - gp);
                    key = key > kk ? key : kk;
                }
            }
            atomicMax(&amax_s[lq], key);
        }
    }
    __syncthreads();
    if (tid < 128 && q0 + tid < NP)
        atomicMax(&amax[(size_t)bh * NP + q0 + tid], amax_s[tid]);
}

// ---------------- decode packed argmax -> packed (ix, iy) bytes ----------
__global__ __launch_bounds__(256) void decode_kernel(
    const u64_t* __restrict__ amax, uchar_t* __restrict__ gidx)
{
    const int t = blockIdx.x * 256 + threadIdx.x;
    if (t >= NBH * NP) return;
    const int idx = 899 - (int)(unsigned)(amax[t] & 0xFFFFFFFFull);
    gidx[2*t]   = (uchar_t)(idx % SIDE);
    gidx[2*t+1] = (uchar_t)(idx / SIDE);
}

// ---------------- gaussian modulate + scale + softmax; fp16 S in, fp16 ch-last S2 out ---------
// r13: r9's one-head-per-wave structure + WIDER loads: Sh read as uint2 (4 fp16/lane/step,
// 4 steps vs 8), gidx as uint2. Same rv[16] live state -- avoids r6's register-doubling
// trap (that regression came from head-interleaving, not the load width).
// Also zeroes `out` for the conv pass (p==0 blocks; ordered before conv by stream order).
__global__ __launch_bounds__(512) void modulate_softmax_kernel(
    const ushort_t* __restrict__ S, const uchar_t* __restrict__ gidx, ushort_t* __restrict__ S2,
    float* __restrict__ out)
{
    __shared__ __align__(16) ushort_t ob[NP][NH];  // 14.4 KB
    __shared__ float TX[SIDE], TY[SIDE];

    const int p = blockIdx.x;
    const int b = blockIdx.y;
    const int tid = threadIdx.x;
    const int lane = tid & 63;
    const int h = tid >> 6;      // wave index == head

    if (p == 0)
        for (int q = tid; q < NP; q += 512) out[(size_t)b*NP + q] = 0.f;

    const float ax = -1.f + (2.f/29.f) * (float)(p % SIDE);
    const float ay = -1.f + (2.f/29.f) * (float)(p / SIDE);

    if (tid < SIDE) {
        const float d = ax - (float)tid;
        TX[tid] = __expf(-d*d * 0.02f);                 // 1/(2*sigma^2), sigma=5
    } else if (tid >= 64 && tid < 64 + SIDE) {
        const int j = tid - 64;
        const float d = ay - (float)j;
        TY[j] = __expf(-d*d * 0.02f);
    }
    __syncthreads();

    {
        const ushort_t* row = S + (size_t)(b*NH + h)*SSZ + (size_t)p*NP;
        const uchar_t* gp = gidx + (size_t)(b*NH + h)*NP*2;

        float rv[16];
        float lmax = -3.4e38f;
        #pragma unroll
        for (int i = 0; i < 4; ++i) {
            const int q4 = 4*lane + 256*i;       // quad (q4..q4+3); 900%4==0 -> all-or-none
            float v0 = -3.4e38f, v1 = -3.4e38f, v2 = -3.4e38f, v3 = -3.4e38f;
            if (q4 < NP) {
                const uint2 u = *(const uint2*)(row + q4);     // 4 fp16
                const uint2 g = *(const uint2*)(gp + 2*q4);    // 4 x (ix,iy) byte pairs
                const uchar_t* gb = (const uchar_t*)&g;
                v0 = h2f((ushort_t)(u.x & 0xFFFFu)) * TX[gb[0]] * TY[gb[1]] * 0.125f;
                v1 = h2f((ushort_t)(u.x >> 16))     * TX[gb[2]] * TY[gb[3]] * 0.125f;
                v2 = h2f((ushort_t)(u.y & 0xFFFFu)) * TX[gb[4]] * TY[gb[5]] * 0.125f;
                v3 = h2f((ushort_t)(u.y >> 16))     * TX[gb[6]] * TY[gb[7]] * 0.125f;
            }
            rv[4*i+0] = v0;  rv[4*i+1] = v1;  rv[4*i+2] = v2;  rv[4*i+3] = v3;
            lmax = fmaxf(lmax, fmaxf(fmaxf(v0, v1), fmaxf(v2, v3)));
        }
        #pragma unroll
        for (int off = 32; off > 0; off >>= 1)
            lmax = fmaxf(lmax, __shfl_xor(lmax, off, 64));

        float lsum = 0.f;
        #pragma unroll
        for (int i = 0; i < 16; ++i) {
            const int q = 4*lane + 256*(i >> 2) + (i & 3);
            const float e = (q < NP) ? __expf(rv[i] - lmax) : 0.f;
            rv[i] = e;
            lsum += e;
        }
        #pragma unroll
        for (int off = 32; off > 0; off >>= 1)
            lsum += __shfl_xor(lsum, off, 64);
        const float inv = 1.f / lsum;

        #pragma unroll
        for (int i = 0; i < 4; ++i) {
            const int q4 = 4*lane + 256*i;
            if (q4 < NP) {
                ob[q4+0][h] = f2h(rv[4*i+0] * inv);
                ob[q4+1][h] = f2h(rv[4*i+1] * inv);
                ob[q4+2][h] = f2h(rv[4*i+2] * inv);
                ob[q4+3][h] = f2h(rv[4*i+3] * inv);
            }
        }
    }
    __syncthreads();
    for (int q = tid; q < NP; q += 512)
        *(uint4*)(S2 + (((size_t)b*NP + p)*NP + q)*NH) = *(const uint4*)&ob[q][0];
}

// ---------------- MFMA fused conv1+conv2+value-reduce (fp16) ----------------
// PROVEN 71.6us version (r1/r3) -- FROZEN. The register file is fully committed
// (64 VGPR + accumulator AGPRs = the full 128-reg (256,4) budget): every added live
// value (r2 bias-fold, r4/r5 ring regs, r8 b1r[16]) spilled to scratch and ballooned
// WRITE_SIZE. Do not add state; do not restructure.
__global__ __launch_bounds__(256, 4) void conv_mfma_kernel(
    const ushort_t* __restrict__ S2, const ushort_t* __restrict__ w1b,
    const ushort_t* __restrict__ w2b,
    const float* __restrict__ b1, const float* __restrict__ b2,
    const float* __restrict__ value, float* __restrict__ out)
{
    __shared__ __align__(16) ushort_t a_s[4][13][34][8];    // 28,288 B: attn tile, ch-last fp16
    __shared__ __align__(16) ushort_t c1row[4][34][40];     // 10,880 B: one c1 row per wave

    const int tid  = threadIdx.x;
    const int lane = tid & 63;
    const int w    = tid >> 6;
    const int b    = blockIdx.z;
    const int gx0  = blockIdx.x * 30;
    const int gy0w = blockIdx.y * 36 + w * 9;

    // zero guard rows x=32,33 (read by group-1 fragments; results discarded via vseg=0)
    c1row[w][32 + (lane >> 5)][lane & 31] = 0;

    // ---- stage attn tile (zeros outside image); per-wave, no barrier ----
    for (int i = lane; i < 13*34; i += 64) {
        const int ai = i / 34, xi = i - ai*34;
        const int gp = gy0w - 2 + ai, gq = gx0 - 2 + xi;
        uint4 v = make_uint4(0u,0u,0u,0u);
        if ((unsigned)gp < (unsigned)NP && (unsigned)gq < (unsigned)NP)
            v = *(const uint4*)(S2 + (((size_t)b*NP + gp)*NP + gq)*NH);
        *(uint4*)&a_s[w][ai][xi][0] = v;
    }

    // ---- weight fragments (global, L2-cached) ----
    h8v w1f[5], w2f[9];
    #pragma unroll
    for (int c = 0; c < 5; ++c) w1f[c] = *(const h8v*)(w1b + ((size_t)c*64 + lane)*8);
    #pragma unroll
    for (int t = 0; t < 9; ++t) w2f[t] = *(const h8v*)(w2b + ((size_t)t*64 + lane)*8);

    const float b1v = b1[lane & 31];
    const float b2v = ((lane & 15) < 8) ? b2[lane & 15] : 0.f;

    const int m    = lane & 31;    // conv1 A-frag M index (c1 x)
    const int half = lane >> 5;    // conv1 K-half (tap-in-pair)
    const int m16  = lane & 15;    // conv2 A-frag M index
    const int qd   = lane >> 4;    // conv2 K-quad

    float vseg[2][4];
    #pragma unroll
    for (int g = 0; g < 2; ++g)
        #pragma unroll
        for (int r = 0; r < 4; ++r) {
            const int ql = g*16 + qd*4 + r;
            vseg[g][r] = (ql < 30) ? value[b*NP + gx0 + ql] : 0.f;
        }

    auto lda = [&](int y, int x) -> h8v {
        return *(const h8v*)&a_s[w][y][x][0];   // single ds_read_b128
    };

    f4v o0[3] = {}, o1[3] = {};   // rolling accumulators, out row yo -> slot yo%3

    #pragma unroll
    for (int yc = 0; yc < 11; ++yc) {
        // ---- conv1: c1 row yc (image row gy0w-1+yc) -> c1row[w] ----
        {
            const bool rowok = (unsigned)(gy0w - 1 + yc) < (unsigned)NP;
            const h8v A0 = lda(yc,        m + half);            // taps 0,1
            const h8v A1 = lda(yc + half, half ? m : (m + 2));  // taps 2,3
            const h8v A2 = lda(yc + 1,    m + 1 + half);        // taps 4,5
            const h8v A3 = lda(yc + 2,    m + half);            // taps 6,7
            const h8v A4 = lda(yc + 2,    m + 2);               // tap 8
            f16v acc = {};
            acc = __builtin_amdgcn_mfma_f32_32x32x16_f16(A0, w1f[0], acc, 0, 0, 0);
            acc = __builtin_amdgcn_mfma_f32_32x32x16_f16(A1, w1f[1], acc, 0, 0, 0);
            acc = __builtin_amdgcn_mfma_f32_32x32x16_f16(A2, w1f[2], acc, 0, 0, 0);
            acc = __builtin_amdgcn_mfma_f32_32x32x16_f16(A3, w1f[3], acc, 0, 0, 0);
            acc = __builtin_amdgcn_mfma_f32_32x32x16_f16(A4, w1f[4], acc, 0, 0, 0);
            #pragma unroll
            for (int r = 0; r < 16; ++r) {
                const int x_l = (r & 3) + 8*(r >> 2) + 4*half;   // D row = c1 x
                float f = fmaxf(acc[r] + b1v, 0.f);
                const bool ok = rowok && ((unsigned)(gx0 - 1 + x_l) < (unsigned)NP);
                f = ok ? f : 0.f;                                // SAME-pad: OOB c1 = 0
                c1row[w][x_l][lane & 31] = f2h(f);
            }
        }
        // same-wave LDS write->read: DS ops in order per wave; drain counter
        asm volatile("s_waitcnt lgkmcnt(0)" ::: "memory");

        // ---- conv2: read 6 fragments once (aligned b128), scatter into rows yc-2..yc ----
        #pragma unroll
        for (int dx = 0; dx < 3; ++dx) {
            const int x0 = m16 + dx, x1 = 16 + m16 + dx;
            const h8v a0 = *(const h8v*)&c1row[w][x0][qd*8];
            const h8v a1 = *(const h8v*)&c1row[w][x1][qd*8];
            #pragma unroll
            for (int dy = 0; dy < 3; ++dy) {
                const int yo = yc - dy;
                if (yo < 0 || yo > 8) continue;
                const int sl = yo % 3;
                o0[sl] = __builtin_amdgcn_mfma_f32_16x16x32_f16(a0, w2f[dy*3+dx], o0[sl], 0, 0, 0);
                o1[sl] = __builtin_amdgcn_mfma_f32_16x16x32_f16(a1, w2f[dy*3+dx], o1[sl], 0, 0, 0);
            }
        }

        // ---- out row yc-2 complete: epilogue + reset slot ----
        if (yc >= 2) {
            const int yo = yc - 2;
            const int sl = yo % 3;
            float s = 0.f;
            const bool ocok = (lane & 15) < 8;
            #pragma unroll
            for (int r = 0; r < 4; ++r) {
                const float f0 = fmaxf(o0[sl][r] + b2v, 0.f);
                const float f1 = fmaxf(o1[sl][r] + b2v, 0.f);
                s += ocok ? f0 * vseg[0][r] : 0.f;
                s += ocok ? f1 * vseg[1][r] : 0.f;
            }
            #pragma unroll
            for (int off = 32; off > 0; off >>= 1)
                s += __shfl_down(s, off, 64);
            if (lane == 0)
                atomicAdd(out + (size_t)b*NP + (gy0w + yo), s * 0.125f);
            o0[sl] = (f4v){0.f,0.f,0.f,0.f};
            o1[sl] = (f4v){0.f,0.f,0.f,0.f};
        }
    }
}

extern "C" void kernel_launch(void* const* d_in, const int* in_sizes, int n_in,
                              void* d_out, int out_size, void* d_ws, size_t ws_size,
                              hipStream_t stream)
{
    const float* query = (const float*)d_in[0];
    const float* key_t = (const float*)d_in[1];
    const float* value = (const float*)d_in[2];
    const float* Wq    = (const float*)d_in[3];
    const float* bq    = (const float*)d_in[4];
    const float* Wk    = (const float*)d_in[5];
    const float* bk    = (const float*)d_in[6];
    const float* c1w   = (const float*)d_in[7];
    const float* c1b   = (const float*)d_in[8];
    const float* c2w   = (const float*)d_in[9];
    const float* c2b   = (const float*)d_in[10];
    float* out = (float*)d_out;

    // packed pre-split fp16 Q/K: [bh][p][hi 64 | lo 64] -> 2 x 7,372,800 ushorts
    ushort_t* Qhl = (ushort_t*)d_ws;
    ushort_t* Khl = Qhl + (size_t)NBH*NP*128;
    u64_t*    amax = (u64_t*)(Khl + (size_t)NBH*NP*128);    // 32*900 u64
    uchar_t*  gidx = (uchar_t*)(amax + (size_t)NBH*NP);     // 32*900*2 B
    ushort_t* Sh   = (ushort_t*)(gidx + (size_t)NBH*NP*2 + 256);  // fp16 scores, 51.84 MB
    ushort_t* S2   = Sh + (size_t)NBH*SSZ;                  // fp16 attn ch-last, 51.84 MB
    ushort_t* w1b  = S2 + (size_t)NB*NP*NP*NH;
    ushort_t* w2b  = w1b + 5*64*8;

    proj_kernel<<<dim3(58, 4, 2), 256, 0, stream>>>(query, key_t, Wq, bq, Wk, bk,
                                                    Qhl, Khl, c1w, c2w, w1b, w2b, amax);
    scores_kernel<<<dim3(3840), 256, 0, stream>>>(Qhl, Khl, Sh, amax);
    decode_kernel<<<dim3(113), 256, 0, stream>>>(amax, gidx);
    modulate_softmax_kernel<<<dim3(900, 4), 512, 0, stream>>>(Sh, gidx, S2, out);
    conv_mfma_kernel<<<dim3(30, 25, 4), 256, 0, stream>>>(S2, w1b, w2b, c1b, c2b, value, out);
}

// Round 15
// 234.490 us; speedup vs baseline: 1.0429x; 1.0429x over previous
//
#include <hip/hip_runtime.h>

#define NB 4
#define NP 900
#define ND 512
#define NH 8
#define NDK 64
#define NROWS (NB*NP)          // 3600
#define SSZ (NP*NP)            // 810000
#define NBH (NB*NH)            // 32
#define SIDE 30

typedef unsigned short ushort_t;
typedef unsigned char uchar_t;
typedef unsigned long long u64_t;
typedef __attribute__((ext_vector_type(8)))  _Float16 h8v;
typedef __attribute__((ext_vector_type(4)))  float  f4v;
typedef __attribute__((ext_vector_type(16))) float  f16v;

__device__ __forceinline__ ushort_t f2h(float f) {
    union { _Float16 h; ushort_t u; } c; c.h = (_Float16)f; return c.u;
}
__device__ __forceinline__ float h2f(ushort_t u) {
    union { _Float16 h; ushort_t u; } c; c.u = u; return (float)c.h;
}
// order-preserving f32 -> u32 (total order; equal floats -> equal codes)
__device__ __forceinline__ unsigned int fenc(float v) {
    unsigned int b = __float_as_uint(v);
    return (b & 0x80000000u) ? ~b : (b | 0x80000000u);
}

// split one float4 into fp16 hi/lo and store to a 128-ushort LDS row (swizzled 16B chunks)
__device__ __forceinline__ void split_store(char* rowp, int r, int c4, float4 v) {
    const int ch  = (c4 >> 1) ^ (r & 7);
    const int off = (c4 & 1) * 8;
    const float f[4] = {v.x, v.y, v.z, v.w};
    ushort_t hi[4], lo[4];
    #pragma unroll
    for (int j = 0; j < 4; ++j) {
        hi[j] = f2h(f[j]);
        lo[j] = f2h(f[j] - h2f(hi[j]));
    }
    uint2 u;
    u.x = (unsigned)hi[0] | ((unsigned)hi[1] << 16);
    u.y = (unsigned)hi[2] | ((unsigned)hi[3] << 16);
    *(uint2*)(rowp + ch*16 + off) = u;
    u.x = (unsigned)lo[0] | ((unsigned)lo[1] << 16);
    u.y = (unsigned)lo[2] | ((unsigned)lo[3] << 16);
    *(uint2*)(rowp + (ch + 8)*16 + off) = u;
}

// ---------------- projection via split-fp16 MFMA (3-term ~= f32 exact) ----------------
// out = X · W^T + bias, written PRE-SPLIT in PACKED [bh][p][hi 0..63 | lo 64..127] fp16
// layout (r11-proven). Bias folded into accumulator init. Absorbs prep_weights (x==57).
__global__ __launch_bounds__(256, 3) void proj_kernel(
    const float* __restrict__ query, const float* __restrict__ key_t,
    const float* __restrict__ Wq, const float* __restrict__ bq,
    const float* __restrict__ Wk, const float* __restrict__ bk,
    ushort_t* __restrict__ Qhl, ushort_t* __restrict__ Khl,
    const float* __restrict__ c1w, const float* __restrict__ c2w,
    ushort_t* __restrict__ w1b, ushort_t* __restrict__ w2b,
    u64_t* __restrict__ amax)
{
    // ---- folded prep_weights: grid.x==57 slot (one working block, others exit) ----
    if (blockIdx.x == 57) {
        if (blockIdx.z == 1 && blockIdx.y == 0) {
            const int tid = threadIdx.x;
            for (int i = tid; i < 5*64; i += 256) {
                const int c = i >> 6, l = i & 63;
                const int oc = l & 31, hf = l >> 5;
                #pragma unroll
                for (int j = 0; j < 8; ++j) {
                    float wv;
                    if (c < 4)      wv = c1w[(oc*8 + j)*9 + (2*c + hf)];
                    else            wv = hf ? 0.f : c1w[(oc*8 + j)*9 + 8];
                    w1b[(i)*8 + j] = f2h(wv);
                }
            }
            for (int i = tid; i < 9*64; i += 256) {
                const int t = i >> 6, l = i & 63;
                const int n = l & 15, qd = l >> 4;
                #pragma unroll
                for (int j = 0; j < 8; ++j) {
                    const int k = qd*8 + j;
                    const float wv = (n < 8) ? c2w[(n*32 + k)*9 + t] : 0.f;
                    w2b[(i)*8 + j] = f2h(wv);
                }
            }
        }
        return;
    }

    __shared__ __align__(16) ushort_t As[64][128];    // 16 KB: [row][hi 0..63 | lo 64..127]
    __shared__ __align__(16) ushort_t Bs[128][128];   // 32 KB

    const float *X, *W, *bias;
    ushort_t *Ohl;
    if (blockIdx.z == 0) { X = query; W = Wq; bias = bq; Ohl = Qhl; }
    else                 { X = key_t; W = Wk; bias = bk; Ohl = Khl; }

    // fused amax zeroing (stream-ordered before scores_kernel); 228 blocks cover 28800
    if (blockIdx.z == 0) {
        const int t = (blockIdx.y * 57 + blockIdx.x) * 256 + threadIdx.x;
        if (t < NBH * NP) amax[t] = 0ull;
    }

    const int m0 = blockIdx.x * 64;      // row tile (57 tiles over 3600)
    const int n0 = blockIdx.y * 128;     // col tile (4 tiles over 512)
    const int tid  = threadIdx.x;
    const int lane = tid & 63;
    const int w    = tid >> 6;
    const int ln = lane & 31, lh = lane >> 5;
    const int wr = (w >> 1) * 32;        // wave: 32 rows x 64 cols
    const int wc = (w & 1) * 64;

    f16v acc[2];
    #pragma unroll
    for (int cb = 0; cb < 2; ++cb) {
        const float bv = bias[n0 + wc + cb*32 + ln];
        #pragma unroll
        for (int r = 0; r < 16; ++r) acc[cb][r] = bv;
    }

    auto ldA = [&](int row, int ch) -> h8v {
        return *(const h8v*)((const char*)&As[row][0] + ((ch ^ (row & 7)) << 4));
    };
    auto ldB = [&](int row, int ch) -> h8v {
        return *(const h8v*)((const char*)&Bs[row][0] + ((ch ^ (row & 7)) << 4));
    };

    for (int kt = 0; kt < 8; ++kt) {
        const int kb = kt * 64;
        #pragma unroll
        for (int i = 0; i < 4; ++i) {
            const int idx = tid + i * 256;           // 0..1023 : A rows
            const int r = idx >> 4, c4 = idx & 15;
            float4 v = make_float4(0.f, 0.f, 0.f, 0.f);
            if (m0 + r < NROWS) v = *(const float4*)(X + (size_t)(m0 + r) * ND + kb + c4*4);
            split_store((char*)&As[r][0], r, c4, v);
        }
        #pragma unroll
        for (int i = 0; i < 8; ++i) {
            const int idx = tid + i * 256;           // 0..2047 : B rows (W rows, always valid)
            const int r = idx >> 4, c4 = idx & 15;
            const float4 v = *(const float4*)(W + (size_t)(n0 + r) * ND + kb + c4*4);
            split_store((char*)&Bs[r][0], r, c4, v);
        }
        __syncthreads();

        #pragma unroll
        for (int ks = 0; ks < 4; ++ks) {
            const int chH = ks*2 + lh;
            const h8v a_h = ldA(wr + ln, chH);
            const h8v a_l = ldA(wr + ln, chH + 8);
            #pragma unroll
            for (int cb = 0; cb < 2; ++cb) {
                const int col = wc + cb*32 + ln;
                const h8v b_h = ldB(col, chH);
                const h8v b_l = ldB(col, chH + 8);
                acc[cb] = __builtin_amdgcn_mfma_f32_32x32x16_f16(a_h, b_h, acc[cb], 0, 0, 0);
                acc[cb] = __builtin_amdgcn_mfma_f32_32x32x16_f16(a_h, b_l, acc[cb], 0, 0, 0);
                acc[cb] = __builtin_amdgcn_mfma_f32_32x32x16_f16(a_l, b_h, acc[cb], 0, 0, 0);
            }
        }
        __syncthreads();
    }

    // epilogue: split to fp16 hi/lo, packed row layout [bh][p][hi|lo]
    #pragma unroll
    for (int cb = 0; cb < 2; ++cb) {
        const int col = n0 + wc + cb*32 + ln;
        const int h = col >> 6, dk = col & 63;
        #pragma unroll
        for (int r = 0; r < 16; ++r) {
            const int gi = m0 + wr + ((r & 3) + 8*(r >> 2) + 4*lh);
            if (gi < NROWS) {
                const int bb = gi / NP, p = gi - bb * NP;
                const float v = acc[cb][r];
                const ushort_t hi = f2h(v);
                const ushort_t lo = f2h(v - h2f(hi));
                ushort_t* dst = Ohl + ((size_t)(bb*NH + h)*NP + p)*128 + dk;
                dst[0]  = hi;
                dst[64] = lo;
            }
        }
    }
}

// ---------------- scores via split-fp16 MFMA (3-term compensation ~= f32 exact) ----------
// S = Qh*Kh + Qh*Kl + Ql*Kh  (Ql*Kl ~ 2^-22 relative, dropped).
// r12-proven: 64(p) x 128(q) tile, 49KB LDS -> 3 blocks/CU. Staging is pure copy
// (r11 packed layout). Fused per-column argmax; stores S as fp16.
__global__ __launch_bounds__(256, 3) void scores_kernel(
    const ushort_t* __restrict__ Qhl, const ushort_t* __restrict__ Khl,
    ushort_t* __restrict__ Sh, u64_t* __restrict__ amax)
{
    __shared__ __align__(16) ushort_t Qs[64][128];    // 16 KB: [row][0..63]=hi, [64..127]=lo
    __shared__ __align__(16) ushort_t Ks[128][128];   // 32 KB
    __shared__ u64_t amax_s[128];

    // XCD-contiguous swizzle: 3840 blocks -> 480-block chunks per XCD (bijective)
    const int lin = blockIdx.x;
    const int swz = (lin & 7) * 480 + (lin >> 3);
    const int bh  = swz / 120;                 // 120 tiles per head (15 p x 8 q)
    const int tt  = swz - bh * 120;
    const int p0  = (tt >> 3) * 64;            // query-row tile (15 tiles over 900)
    const int q0  = (tt & 7) * 128;            // key-col tile

    const ushort_t* Qhlb = Qhl + (size_t)bh * NP * 128;
    const ushort_t* Khlb = Khl + (size_t)bh * NP * 128;
    const int tid  = threadIdx.x;
    const int lane = tid & 63;
    const int w    = tid >> 6;

    if (tid < 128) amax_s[tid] = 0ull;

    // ---- stage (pure copy): Q 64 rows + K 128 rows, 16 b128 chunks each; 12/thread ----
    #pragma unroll
    for (int i = 0; i < 12; ++i) {
        const int idx = tid + i * 256;          // 0..3071 (idx<1024 -> Q, else K)
        int r, c8;
        const ushort_t* src;
        char* rowp;
        int base;
        if (idx < 1024) {
            r = idx >> 4; c8 = idx & 15;
            src = Qhlb; rowp = (char*)&Qs[r][0]; base = p0;
        } else {
            const int k = idx - 1024;
            r = k >> 4; c8 = k & 15;
            src = Khlb; rowp = (char*)&Ks[r][0]; base = q0;
        }
        uint4 v = make_uint4(0u,0u,0u,0u);
        if (base + r < NP) v = *(const uint4*)(src + (size_t)(base + r)*128 + c8*8);
        const int ch = ((c8 & 7) ^ (r & 7)) | (c8 & 8);
        *(uint4*)(rowp + ch*16) = v;
    }
    __syncthreads();

    const int ln = lane & 31;
    const int lh = lane >> 5;
    const int wr = (w & 1) * 32;    // wave rows (32 of 64)
    const int wc = (w >> 1) * 64;   // wave cols (64 of 128)

    auto ldQ = [&](int row, int ch) -> h8v {
        return *(const h8v*)((const char*)&Qs[row][0] + ((ch ^ (row & 7)) << 4));
    };
    auto ldK = [&](int row, int ch) -> h8v {
        return *(const h8v*)((const char*)&Ks[row][0] + ((ch ^ (row & 7)) << 4));
    };

    f16v acc[2] = {};

    #pragma unroll
    for (int ks = 0; ks < 4; ++ks) {
        const int chH = ks*2 + lh;          // hi chunk for this lane-half; lo = chH+8
        const h8v ah = ldQ(wr + ln, chH);
        const h8v al = ldQ(wr + ln, chH + 8);
        #pragma unroll
        for (int cb = 0; cb < 2; ++cb) {
            const int col = wc + cb*32 + ln;
            const h8v bh_ = ldK(col, chH);
            const h8v bl_ = ldK(col, chH + 8);
            acc[cb] = __builtin_amdgcn_mfma_f32_32x32x16_f16(ah, bh_, acc[cb], 0, 0, 0);
            acc[cb] = __builtin_amdgcn_mfma_f32_32x32x16_f16(ah, bl_, acc[cb], 0, 0, 0);
            acc[cb] = __builtin_amdgcn_mfma_f32_32x32x16_f16(al, bh_, acc[cb], 0, 0, 0);
        }
    }

    // ---- epilogue: fp16 store + fused column argmax ----
    ushort_t* Sb = Sh + (size_t)bh * SSZ;
    #pragma unroll
    for (int cb = 0; cb < 2; ++cb) {
        const int lq = wc + cb*32 + ln;
        const int gq = q0 + lq;
        if (gq < NP) {
            u64_t key = 0ull;
            #pragma unroll
            for (int r = 0; r < 16; ++r) {
                const int gp = p0 + wr + ((r & 3) + 8*(r >> 2) + 4*lh);
                if (gp < NP) {
                    const float v = acc[cb][r];
                    Sb[(size_t)gp * NP + gq] = f2h(v);
                    const u64_t kk = ((u64_t)fenc(v) << 32) | (unsigned)(899 - gp);
                    key = key > kk ? key : kk;
                }
            }
            atomicMax(&amax_s[lq], key);
        }
    }
    __syncthreads();
    if (tid < 128 && q0 + tid < NP)
        atomicMax(&amax[(size_t)bh * NP + q0 + tid], amax_s[tid]);
}

// ---------------- decode packed argmax -> packed (ix, iy) bytes ----------
__global__ __launch_bounds__(256) void decode_kernel(
    const u64_t* __restrict__ amax, uchar_t* __restrict__ gidx)
{
    const int t = blockIdx.x * 256 + threadIdx.x;
    if (t >= NBH * NP) return;
    const int idx = 899 - (int)(unsigned)(amax[t] & 0xFFFFFFFFull);
    gidx[2*t]   = (uchar_t)(idx % SIDE);
    gidx[2*t+1] = (uchar_t)(idx / SIDE);
}

// ---------------- gaussian modulate + scale + softmax; fp16 S in, fp16 ch-last S2 out ---------
// r12-PROVEN form restored verbatim (one head per wave, scalar 4B loads). r13/r14's
// uint2 vectorization regressed ~8us: halving outstanding loads per wave reduced MLP
// on this latency-bound kernel. 8x4B loads is the measured local optimum.
// Also zeroes `out` for the conv pass (p==0 blocks; ordered before conv by stream order).
__global__ __launch_bounds__(512) void modulate_softmax_kernel(
    const ushort_t* __restrict__ S, const uchar_t* __restrict__ gidx, ushort_t* __restrict__ S2,
    float* __restrict__ out)
{
    __shared__ __align__(16) ushort_t ob[NP][NH];  // 14.4 KB
    __shared__ float TX[SIDE], TY[SIDE];

    const int p = blockIdx.x;
    const int b = blockIdx.y;
    const int tid = threadIdx.x;
    const int lane = tid & 63;
    const int h = tid >> 6;      // wave index == head

    if (p == 0)
        for (int q = tid; q < NP; q += 512) out[(size_t)b*NP + q] = 0.f;

    const float ax = -1.f + (2.f/29.f) * (float)(p % SIDE);
    const float ay = -1.f + (2.f/29.f) * (float)(p / SIDE);

    if (tid < SIDE) {
        const float d = ax - (float)tid;
        TX[tid] = __expf(-d*d * 0.02f);                 // 1/(2*sigma^2), sigma=5
    } else if (tid >= 64 && tid < 64 + SIDE) {
        const int j = tid - 64;
        const float d = ay - (float)j;
        TY[j] = __expf(-d*d * 0.02f);
    }
    __syncthreads();

    {
        const ushort_t* row = S + (size_t)(b*NH + h)*SSZ + (size_t)p*NP;
        const uchar_t* gp = gidx + (size_t)(b*NH + h)*NP*2;

        float rv[16];
        float lmax = -3.4e38f;
        #pragma unroll
        for (int i = 0; i < 8; ++i) {
            const int q2 = 2*lane + 128*i;      // even; pair (q2, q2+1)
            float v0 = -3.4e38f, v1 = -3.4e38f;
            if (q2 < NP) {                       // NP even -> pair fully valid
                const unsigned u = *(const unsigned*)(row + q2);
                const uchar4 g4 = *(const uchar4*)(gp + 2*q2);   // ix0,iy0,ix1,iy1
                v0 = h2f((ushort_t)(u & 0xFFFFu)) * TX[g4.x] * TY[g4.y] * 0.125f;
                v1 = h2f((ushort_t)(u >> 16))     * TX[g4.z] * TY[g4.w] * 0.125f;
            }
            rv[2*i]   = v0;
            rv[2*i+1] = v1;
            lmax = fmaxf(lmax, fmaxf(v0, v1));
        }
        #pragma unroll
        for (int off = 32; off > 0; off >>= 1)
            lmax = fmaxf(lmax, __shfl_xor(lmax, off, 64));

        float lsum = 0.f;
        #pragma unroll
        for (int i = 0; i < 16; ++i) {
            const int q = 2*lane + 128*(i >> 1) + (i & 1);
            const float e = (q < NP) ? __expf(rv[i] - lmax) : 0.f;
            rv[i] = e;
            lsum += e;
        }
        #pragma unroll
        for (int off = 32; off > 0; off >>= 1)
            lsum += __shfl_xor(lsum, off, 64);
        const float inv = 1.f / lsum;

        #pragma unroll
        for (int i = 0; i < 8; ++i) {
            const int q2 = 2*lane + 128*i;
            if (q2 < NP) {
                ob[q2][h]   = f2h(rv[2*i]   * inv);
                ob[q2+1][h] = f2h(rv[2*i+1] * inv);
            }
        }
    }
    __syncthreads();
    for (int q = tid; q < NP; q += 512)
        *(uint4*)(S2 + (((size_t)b*NP + p)*NP + q)*NH) = *(const uint4*)&ob[q][0];
}

// ---------------- MFMA fused conv1+conv2+value-reduce (fp16) ----------------
// PROVEN 71.6us version (r1/r3) -- FROZEN. The register file is fully committed
// (64 VGPR + accumulator AGPRs = the full 128-reg (256,4) budget): every added live
// value (r2 bias-fold, r4/r5 ring regs, r8 b1r[16]) spilled to scratch and ballooned
// WRITE_SIZE. Do not add state; do not restructure.
__global__ __launch_bounds__(256, 4) void conv_mfma_kernel(
    const ushort_t* __restrict__ S2, const ushort_t* __restrict__ w1b,
    const ushort_t* __restrict__ w2b,
    const float* __restrict__ b1, const float* __restrict__ b2,
    const float* __restrict__ value, float* __restrict__ out)
{
    __shared__ __align__(16) ushort_t a_s[4][13][34][8];    // 28,288 B: attn tile, ch-last fp16
    __shared__ __align__(16) ushort_t c1row[4][34][40];     // 10,880 B: one c1 row per wave

    const int tid  = threadIdx.x;
    const int lane = tid & 63;
    const int w    = tid >> 6;
    const int b    = blockIdx.z;
    const int gx0  = blockIdx.x * 30;
    const int gy0w = blockIdx.y * 36 + w * 9;

    // zero guard rows x=32,33 (read by group-1 fragments; results discarded via vseg=0)
    c1row[w][32 + (lane >> 5)][lane & 31] = 0;

    // ---- stage attn tile (zeros outside image); per-wave, no barrier ----
    for (int i = lane; i < 13*34; i += 64) {
        const int ai = i / 34, xi = i - ai*34;
        const int gp = gy0w - 2 + ai, gq = gx0 - 2 + xi;
        uint4 v = make_uint4(0u,0u,0u,0u);
        if ((unsigned)gp < (unsigned)NP && (unsigned)gq < (unsigned)NP)
            v = *(const uint4*)(S2 + (((size_t)b*NP + gp)*NP + gq)*NH);
        *(uint4*)&a_s[w][ai][xi][0] = v;
    }

    // ---- weight fragments (global, L2-cached) ----
    h8v w1f[5], w2f[9];
    #pragma unroll
    for (int c = 0; c < 5; ++c) w1f[c] = *(const h8v*)(w1b + ((size_t)c*64 + lane)*8);
    #pragma unroll
    for (int t = 0; t < 9; ++t) w2f[t] = *(const h8v*)(w2b + ((size_t)t*64 + lane)*8);

    const float b1v = b1[lane & 31];
    const float b2v = ((lane & 15) < 8) ? b2[lane & 15] : 0.f;

    const int m    = lane & 31;    // conv1 A-frag M index (c1 x)
    const int half = lane >> 5;    // conv1 K-half (tap-in-pair)
    const int m16  = lane & 15;    // conv2 A-frag M index
    const int qd   = lane >> 4;    // conv2 K-quad

    float vseg[2][4];
    #pragma unroll
    for (int g = 0; g < 2; ++g)
        #pragma unroll
        for (int r = 0; r < 4; ++r) {
            const int ql = g*16 + qd*4 + r;
            vseg[g][r] = (ql < 30) ? value[b*NP + gx0 + ql] : 0.f;
        }

    auto lda = [&](int y, int x) -> h8v {
        return *(const h8v*)&a_s[w][y][x][0];   // single ds_read_b128
    };

    f4v o0[3] = {}, o1[3] = {};   // rolling accumulators, out row yo -> slot yo%3

    #pragma unroll
    for (int yc = 0; yc < 11; ++yc) {
        // ---- conv1: c1 row yc (image row gy0w-1+yc) -> c1row[w] ----
        {
            const bool rowok = (unsigned)(gy0w - 1 + yc) < (unsigned)NP;
            const h8v A0 = lda(yc,        m + half);            // taps 0,1
            const h8v A1 = lda(yc + half, half ? m : (m + 2));  // taps 2,3
            const h8v A2 = lda(yc + 1,    m + 1 + half);        // taps 4,5
            const h8v A3 = lda(yc + 2,    m + half);            // taps 6,7
            const h8v A4 = lda(yc + 2,    m + 2);               // tap 8
            f16v acc = {};
            acc = __builtin_amdgcn_mfma_f32_32x32x16_f16(A0, w1f[0], acc, 0, 0, 0);
            acc = __builtin_amdgcn_mfma_f32_32x32x16_f16(A1, w1f[1], acc, 0, 0, 0);
            acc = __builtin_amdgcn_mfma_f32_32x32x16_f16(A2, w1f[2], acc, 0, 0, 0);
            acc = __builtin_amdgcn_mfma_f32_32x32x16_f16(A3, w1f[3], acc, 0, 0, 0);
            acc = __builtin_amdgcn_mfma_f32_32x32x16_f16(A4, w1f[4], acc, 0, 0, 0);
            #pragma unroll
            for (int r = 0; r < 16; ++r) {
                const int x_l = (r & 3) + 8*(r >> 2) + 4*half;   // D row = c1 x
                float f = fmaxf(acc[r] + b1v, 0.f);
                const bool ok = rowok && ((unsigned)(gx0 - 1 + x_l) < (unsigned)NP);
                f = ok ? f : 0.f;                                // SAME-pad: OOB c1 = 0
                c1row[w][x_l][lane & 31] = f2h(f);
            }
        }
        // same-wave LDS write->read: DS ops in order per wave; drain counter
        asm volatile("s_waitcnt lgkmcnt(0)" ::: "memory");

        // ---- conv2: read 6 fragments once (aligned b128), scatter into rows yc-2..yc ----
        #pragma unroll
        for (int dx = 0; dx < 3; ++dx) {
            const int x0 = m16 + dx, x1 = 16 + m16 + dx;
            const h8v a0 = *(const h8v*)&c1row[w][x0][qd*8];
            const h8v a1 = *(const h8v*)&c1row[w][x1][qd*8];
            #pragma unroll
            for (int dy = 0; dy < 3; ++dy) {
                const int yo = yc - dy;
                if (yo < 0 || yo > 8) continue;
                const int sl = yo % 3;
                o0[sl] = __builtin_amdgcn_mfma_f32_16x16x32_f16(a0, w2f[dy*3+dx], o0[sl], 0, 0, 0);
                o1[sl] = __builtin_amdgcn_mfma_f32_16x16x32_f16(a1, w2f[dy*3+dx], o1[sl], 0, 0, 0);
            }
        }

        // ---- out row yc-2 complete: epilogue + reset slot ----
        if (yc >= 2) {
            const int yo = yc - 2;
            const int sl = yo % 3;
            float s = 0.f;
            const bool ocok = (lane & 15) < 8;
            #pragma unroll
            for (int r = 0; r < 4; ++r) {
                const float f0 = fmaxf(o0[sl][r] + b2v, 0.f);
                const float f1 = fmaxf(o1[sl][r] + b2v, 0.f);
                s += ocok ? f0 * vseg[0][r] : 0.f;
                s += ocok ? f1 * vseg[1][r] : 0.f;
            }
            #pragma unroll
            for (int off = 32; off > 0; off >>= 1)
                s += __shfl_down(s, off, 64);
            if (lane == 0)
                atomicAdd(out + (size_t)b*NP + (gy0w + yo), s * 0.125f);
            o0[sl] = (f4v){0.f,0.f,0.f,0.f};
            o1[sl] = (f4v){0.f,0.f,0.f,0.f};
        }
    }
}

extern "C" void kernel_launch(void* const* d_in, const int* in_sizes, int n_in,
                              void* d_out, int out_size, void* d_ws, size_t ws_size,
                              hipStream_t stream)
{
    const float* query = (const float*)d_in[0];
    const float* key_t = (const float*)d_in[1];
    const float* value = (const float*)d_in[2];
    const float* Wq    = (const float*)d_in[3];
    const float* bq    = (const float*)d_in[4];
    const float* Wk    = (const float*)d_in[5];
    const float* bk    = (const float*)d_in[6];
    const float* c1w   = (const float*)d_in[7];
    const float* c1b   = (const float*)d_in[8];
    const float* c2w   = (const float*)d_in[9];
    const float* c2b   = (const float*)d_in[10];
    float* out = (float*)d_out;

    // packed pre-split fp16 Q/K: [bh][p][hi 64 | lo 64] -> 2 x 7,372,800 ushorts
    ushort_t* Qhl = (ushort_t*)d_ws;
    ushort_t* Khl = Qhl + (size_t)NBH*NP*128;
    u64_t*    amax = (u64_t*)(Khl + (size_t)NBH*NP*128);    // 32*900 u64
    uchar_t*  gidx = (uchar_t*)(amax + (size_t)NBH*NP);     // 32*900*2 B
    ushort_t* Sh   = (ushort_t*)(gidx + (size_t)NBH*NP*2 + 256);  // fp16 scores, 51.84 MB
    ushort_t* S2   = Sh + (size_t)NBH*SSZ;                  // fp16 attn ch-last, 51.84 MB
    ushort_t* w1b  = S2 + (size_t)NB*NP*NP*NH;
    ushort_t* w2b  = w1b + 5*64*8;

    proj_kernel<<<dim3(58, 4, 2), 256, 0, stream>>>(query, key_t, Wq, bq, Wk, bk,
                                                    Qhl, Khl, c1w, c2w, w1b, w2b, amax);
    scores_kernel<<<dim3(3840), 256, 0, stream>>>(Qhl, Khl, Sh, amax);
    decode_kernel<<<dim3(113), 256, 0, stream>>>(amax, gidx);
    modulate_softmax_kernel<<<dim3(900, 4), 512, 0, stream>>>(Sh, gidx, S2, out);
    conv_mfma_kernel<<<dim3(30, 25, 4), 256, 0, stream>>>(S2, w1b, w2b, c1b, c2b, value, out);
}